// Round 1
// baseline (282.532 us; speedup 1.0000x reference)
//
#include <hip/hip_runtime.h>
#include <hip/hip_bf16.h>
#include <math.h>

// Problem constants
#define B_  8192
#define F_  32
#define V_  64
#define C_  32
#define K_  8
#define KP_ 7
#define EPS_ 1e-6f

// ws layout (floats):
//  [0,248)      : w[f][k]  (31 x 8 gumbel-softmax weights)
//  [256,288)    : offc[c]  = cl[c]-lse_cl - lse_t0[c] - sum_f w[f][0]*lse_self[f][c]
//  [512, 512+444416) : lse_pair[((f*7+k)*64+xc)*32+c]

// ---------------- Kernel A: tiny prep (1 block, 1024 threads) ----------------
__global__ __launch_bounds__(1024)
void prep_kernel(const float* __restrict__ cl, const float* __restrict__ t0,
                 const float* __restrict__ st, const float* __restrict__ sl,
                 const float* __restrict__ un, float* __restrict__ ws) {
    __shared__ float gl[31][8];
    __shared__ float wsm[31][8];
    __shared__ float lse_self[31][32];
    int tid = threadIdx.x;

    // gate logits with gumbel noise; analytic validity mask: valid iff k <= min(f+1, 7)
    if (tid < 248) {
        int f = tid >> 3, k = tid & 7;
        int kmax = min(f + 1, KP_);
        bool valid = (k <= kmax);
        float u = un[tid];
        float g = -logf(-logf(u + EPS_) + EPS_);
        gl[f][k] = valid ? (sl[tid] + g) : -INFINITY;
    }
    __syncthreads();
    // softmax per row -> w
    if (tid < 248) {
        int f = tid >> 3, k = tid & 7;
        float m = -INFINITY;
        #pragma unroll
        for (int j = 0; j < 8; j++) m = fmaxf(m, gl[f][j]);
        float s = 0.f;
        #pragma unroll
        for (int j = 0; j < 8; j++) s += expf(gl[f][j] - m);
        float wv = expf(gl[f][k] - m) / s;
        wsm[f][k] = wv;
        ws[tid] = wv;
    }
    // lse_self[f][c]: reduce over v (stride C_), 992 entries
    if (tid < 992) {
        int f = tid >> 5, c = tid & 31;
        float s = 0.f;
        #pragma unroll 8
        for (int v = 0; v < V_; v++) s += expf(st[(f * V_ + v) * C_ + c]);
        lse_self[f][c] = logf(s);
    }
    __syncthreads();
    // folded per-class offset
    if (tid < 32) {
        int c = tid;
        float scl = 0.f;
        #pragma unroll
        for (int j = 0; j < C_; j++) scl += expf(cl[j]);
        float lse_cl = logf(scl);
        float s0 = 0.f;
        #pragma unroll 8
        for (int v = 0; v < V_; v++) s0 += expf(t0[v * C_ + c]);
        float lse_t0 = logf(s0);
        float acc = cl[c] - lse_cl - lse_t0;
        for (int f = 0; f < 31; f++) acc -= wsm[f][0] * lse_self[f][c];
        ws[256 + c] = acc;
    }
}

// ------------- Kernel B: lse over pair_tables self-value axis ---------------
// one thread per (f,k,xc,c); reduction over a (stride V_*C_ = 2048 floats)
__global__ __launch_bounds__(256)
void lse_pair_kernel(const float* __restrict__ pt, float* __restrict__ lse) {
    int idx = blockIdx.x * 256 + threadIdx.x;   // < 31*7*64*32 = 444416
    int c  = idx & 31;
    int xc = (idx >> 5) & 63;
    int fk = idx >> 11;                          // 0..216
    const float* p = pt + (fk * V_ * V_ + xc) * C_ + c;
    float s = 0.f;
    #pragma unroll 8
    for (int a = 0; a < V_; a++) s += expf(p[a * (V_ * C_)]);
    lse[idx] = logf(s);
}

// ------------------------- Kernel C: main gather ----------------------------
// block = 256 threads = 8 batch rows x 32 classes
__global__ __launch_bounds__(256)
void main_kernel(const int* __restrict__ x, const float* __restrict__ t0,
                 const float* __restrict__ st, const float* __restrict__ pt,
                 const float* __restrict__ ws, float* __restrict__ out) {
    __shared__ int   xsh[256];     // 8 rows x 32 features
    __shared__ float wsh[248];
    __shared__ float offsh[32];
    int tid = threadIdx.x;
    xsh[tid] = x[blockIdx.x * 256 + tid];
    if (tid < 248) wsh[tid] = ws[tid];
    if (tid < 32)  offsh[tid] = ws[256 + tid];
    __syncthreads();

    int c = tid & 31;
    int r = tid >> 5;                 // local batch row 0..7
    const int* xrow = &xsh[r * 32];
    const float* __restrict__ lse = ws + 512;

    float acc = offsh[c] + t0[xrow[0] * C_ + c];

    for (int f = 0; f < 31; f++) {
        int xv = xrow[f + 1];
        acc += wsh[f * 8] * st[(f * V_ + xv) * C_ + c];
        int kmax = min(f + 1, KP_);
        for (int k = 0; k < kmax; k++) {
            int xc = xrow[f - k];               // cond_index[f,k] = f-k
            int fk = f * KP_ + k;
            float pv = pt[((fk * V_ + xv) * V_ + xc) * C_ + c];
            float lv = lse[(fk * V_ + xc) * C_ + c];
            acc += wsh[f * 8 + k + 1] * (pv - lv);
        }
    }
    out[blockIdx.x * 256 + tid] = acc;
}

extern "C" void kernel_launch(void* const* d_in, const int* in_sizes, int n_in,
                              void* d_out, int out_size, void* d_ws, size_t ws_size,
                              hipStream_t stream) {
    const int*   x   = (const int*)  d_in[0];
    // d_in[1] = training (unused)
    const float* cl  = (const float*)d_in[2];
    const float* t0  = (const float*)d_in[3];
    const float* st  = (const float*)d_in[4];
    const float* pt  = (const float*)d_in[5];
    const float* sl  = (const float*)d_in[6];
    const float* un  = (const float*)d_in[7];
    // d_in[8] cond_index, d_in[9] valid_mask: deterministic, computed analytically
    float* ws  = (float*)d_ws;
    float* out = (float*)d_out;

    prep_kernel<<<1, 1024, 0, stream>>>(cl, t0, st, sl, un, ws);
    lse_pair_kernel<<<1736, 256, 0, stream>>>(pt, ws + 512);
    main_kernel<<<1024, 256, 0, stream>>>(x, t0, st, pt, ws, out);
}

// Round 2
// 233.535 us; speedup vs baseline: 1.2098x; 1.2098x over previous
//
#include <hip/hip_runtime.h>
#include <math.h>

// Problem constants
#define B_  8192
#define F_  32
#define V_  64
#define C_  32
#define KP_ 7
#define EPS_ 1e-6f

// ws layout (floats):
//  [0,248)        : w[f][k]  (31 x 8 gumbel-softmax weights)
//  [256,288)      : offc[c]  = cl[c]-lse_cl - lse_t0[c] - sum_f w[f][0]*lse_self[f][c]
//  [512, 512+65536) : G[j][v][c]  (folded t0 / self / pair-lse table, 256 KB)
#define WS_G 512

// ---------------- Kernel A: tiny prep (1 block, 1024 threads) ----------------
__global__ __launch_bounds__(1024)
void prep_kernel(const float* __restrict__ cl, const float* __restrict__ t0,
                 const float* __restrict__ st, const float* __restrict__ sl,
                 const float* __restrict__ un, float* __restrict__ ws) {
    __shared__ float gl[31][8];
    __shared__ float wsm[31][8];
    __shared__ float lse_self[31][32];
    int tid = threadIdx.x;

    // gate logits with gumbel noise; analytic validity: valid iff k <= min(f+1, 7)
    if (tid < 248) {
        int f = tid >> 3, k = tid & 7;
        int kmax = min(f + 1, KP_);
        bool valid = (k <= kmax);
        float u = un[tid];
        float g = -__logf(-__logf(u + EPS_) + EPS_);
        gl[f][k] = valid ? (sl[tid] + g) : -INFINITY;
    }
    __syncthreads();
    if (tid < 248) {
        int f = tid >> 3, k = tid & 7;
        float m = -INFINITY;
        #pragma unroll
        for (int j = 0; j < 8; j++) m = fmaxf(m, gl[f][j]);
        float s = 0.f;
        #pragma unroll
        for (int j = 0; j < 8; j++) s += __expf(gl[f][j] - m);
        float wv = __expf(gl[f][k] - m) / s;
        wsm[f][k] = wv;
        ws[tid] = wv;
    }
    if (tid < 992) {
        int f = tid >> 5, c = tid & 31;
        float s = 0.f;
        #pragma unroll 8
        for (int v = 0; v < V_; v++) s += __expf(st[(f * V_ + v) * C_ + c]);
        lse_self[f][c] = __logf(s);
    }
    __syncthreads();
    if (tid < 32) {
        int c = tid;
        float scl = 0.f;
        #pragma unroll
        for (int j = 0; j < C_; j++) scl += __expf(cl[j]);
        float lse_cl = __logf(scl);
        float s0 = 0.f;
        #pragma unroll 8
        for (int v = 0; v < V_; v++) s0 += __expf(t0[v * C_ + c]);
        float lse_t0 = __logf(s0);
        float acc = cl[c] - lse_cl - lse_t0;
        for (int f = 0; f < 31; f++) acc -= wsm[f][0] * lse_self[f][c];
        ws[256 + c] = acc;
    }
}

// ------- Kernel B (fused): lse over pair_tables + fold into G ---------------
// thread per (j, v, c); j = f-k. Each lse element belongs to exactly one j.
// G[j,v,c] = (j==0 ? t0[v,c] : w[j-1][0]*st[j-1,v,c]) - sum_k w[j+k][k+1]*lse[(j+k)*7+k, v, c]
__global__ __launch_bounds__(256)
void build_g_kernel(const float* __restrict__ t0, const float* __restrict__ st,
                    const float* __restrict__ pt, const float* __restrict__ ws,
                    float* __restrict__ G) {
    int idx = blockIdx.x * 256 + threadIdx.x;   // < 32*64*32 = 65536
    int c = idx & 31, v = (idx >> 5) & 63, j = idx >> 11;
    int nk = min(KP_, 31 - j);                  // k valid while f=j+k < 31 (j==31 -> 0)
    const float* bp[KP_];
    #pragma unroll
    for (int k = 0; k < KP_; k++) {
        int f = j + k;
        int fk = f * KP_ + k;
        bp[k] = pt + (fk * (V_ * V_) + v) * C_ + c;   // + a*(V_*C_) walks the self axis
    }
    float s[KP_];
    #pragma unroll
    for (int k = 0; k < KP_; k++) s[k] = 0.f;
    for (int a = 0; a < V_; a += 2) {
        float l0[KP_], l1[KP_];
        #pragma unroll
        for (int k = 0; k < KP_; k++) if (k < nk) {
            l0[k] = bp[k][a * (V_ * C_)];
            l1[k] = bp[k][(a + 1) * (V_ * C_)];
        }
        #pragma unroll
        for (int k = 0; k < KP_; k++) if (k < nk) {
            s[k] += __expf(l0[k]);
            s[k] += __expf(l1[k]);
        }
    }
    float g = 0.f;
    #pragma unroll
    for (int k = 0; k < KP_; k++) if (k < nk)
        g -= ws[(j + k) * 8 + k + 1] * __logf(s[k]);
    if (j == 0) g += t0[v * C_ + c];
    else        g += ws[(j - 1) * 8] * st[((j - 1) * V_ + v) * C_ + c];
    G[idx] = g;
}

// ------------------------- Kernel C: main gather ----------------------------
// grid = 2 f-chunks x 1024 batch blocks; block = 8 batch rows x 32 classes
__global__ __launch_bounds__(256)
void main_kernel(const int* __restrict__ x, const float* __restrict__ pt,
                 const float* __restrict__ ws, float* __restrict__ out) {
    __shared__ int   xsh[256];
    __shared__ float wsh[248];
    __shared__ float offsh[32];
    int tid = threadIdx.x;
    int fchunk = blockIdx.x >> 10;
    int bblk   = blockIdx.x & 1023;
    xsh[tid] = x[bblk * 256 + tid];
    if (tid < 248) wsh[tid] = ws[tid];
    if (tid < 32)  offsh[tid] = ws[256 + tid];
    __syncthreads();

    const float* __restrict__ G = ws + WS_G;
    int c = tid & 31;
    int r = tid >> 5;
    const int* xrow = &xsh[r * 32];
    float acc = 0.f;

    if (fchunk == 0) {
        acc = offsh[c];
        #pragma unroll
        for (int j = 0; j < 16; j++)
            acc += G[(j * V_ + xrow[j]) * C_ + c];
        // triangular part: f=0..5, k<=f
        for (int f = 0; f < 6; f++) {
            int xv = xrow[f + 1];
            const float* bp = pt + ((f * KP_) * V_ + xv) * (V_ * C_) + c;
            float pv[6];
            for (int k = 0; k <= f; k++)
                pv[k] = bp[k * (V_ * V_ * C_) + xrow[f - k] * C_];
            for (int k = 0; k <= f; k++)
                acc += wsh[f * 8 + k + 1] * pv[k];
        }
        #pragma unroll 2
        for (int f = 6; f < 17; f++) {
            int xv = xrow[f + 1];
            const float* bp = pt + ((f * KP_) * V_ + xv) * (V_ * C_) + c;
            float pv[KP_];
            #pragma unroll
            for (int k = 0; k < KP_; k++)
                pv[k] = bp[k * (V_ * V_ * C_) + xrow[f - k] * C_];
            #pragma unroll
            for (int k = 0; k < KP_; k++)
                acc += wsh[f * 8 + k + 1] * pv[k];
        }
    } else {
        #pragma unroll
        for (int j = 16; j < 32; j++)
            acc += G[(j * V_ + xrow[j]) * C_ + c];
        #pragma unroll 2
        for (int f = 17; f < 31; f++) {
            int xv = xrow[f + 1];
            const float* bp = pt + ((f * KP_) * V_ + xv) * (V_ * C_) + c;
            float pv[KP_];
            #pragma unroll
            for (int k = 0; k < KP_; k++)
                pv[k] = bp[k * (V_ * V_ * C_) + xrow[f - k] * C_];
            #pragma unroll
            for (int k = 0; k < KP_; k++)
                acc += wsh[f * 8 + k + 1] * pv[k];
        }
    }
    atomicAdd(&out[bblk * 256 + tid], acc);
}

extern "C" void kernel_launch(void* const* d_in, const int* in_sizes, int n_in,
                              void* d_out, int out_size, void* d_ws, size_t ws_size,
                              hipStream_t stream) {
    const int*   x   = (const int*)  d_in[0];
    // d_in[1] = training (unused)
    const float* cl  = (const float*)d_in[2];
    const float* t0  = (const float*)d_in[3];
    const float* st  = (const float*)d_in[4];
    const float* pt  = (const float*)d_in[5];
    const float* sl  = (const float*)d_in[6];
    const float* un  = (const float*)d_in[7];
    // d_in[8] cond_index, d_in[9] valid_mask: deterministic, computed analytically
    float* ws  = (float*)d_ws;
    float* out = (float*)d_out;

    hipMemsetAsync(out, 0, (size_t)B_ * C_ * sizeof(float), stream);
    prep_kernel<<<1, 1024, 0, stream>>>(cl, t0, st, sl, un, ws);
    build_g_kernel<<<256, 256, 0, stream>>>(t0, st, pt, ws, ws + WS_G);
    main_kernel<<<2048, 256, 0, stream>>>(x, pt, ws, out);
}

// Round 3
// 231.062 us; speedup vs baseline: 1.2228x; 1.0107x over previous
//
#include <hip/hip_runtime.h>
#include <math.h>

// Problem constants
#define B_  8192
#define F_  32
#define V_  64
#define C_  32
#define KP_ 7
#define EPS_ 1e-6f

// ws layout (floats):
//  [0,248)          : w[f][k]  (31 x 8 gumbel-softmax weights)
//  [256,288)        : offc[c]  = cl[c]-lse_cl - lse_t0[c] - sum_f w[f][0]*lse_self[f][c]
//  [512, 512+65536) : G[j][v][c]  (folded t0 / self / pair-lse table, 256 KB)
#define WS_G 512

// ---------------- Kernel A: tiny prep (1 block, 1024 threads) ----------------
__global__ __launch_bounds__(1024)
void prep_kernel(const float* __restrict__ cl, const float* __restrict__ t0,
                 const float* __restrict__ st, const float* __restrict__ sl,
                 const float* __restrict__ un, float* __restrict__ ws) {
    __shared__ float gl[31][8];
    __shared__ float wsm[31][8];
    __shared__ float lse_self[31][32];
    int tid = threadIdx.x;

    // gate logits with gumbel noise; analytic validity: valid iff k <= min(f+1, 7)
    if (tid < 248) {
        int f = tid >> 3, k = tid & 7;
        int kmax = min(f + 1, KP_);
        bool valid = (k <= kmax);
        float u = un[tid];
        float g = -__logf(-__logf(u + EPS_) + EPS_);
        gl[f][k] = valid ? (sl[tid] + g) : -INFINITY;
    }
    __syncthreads();
    if (tid < 248) {
        int f = tid >> 3, k = tid & 7;
        float m = -INFINITY;
        #pragma unroll
        for (int j = 0; j < 8; j++) m = fmaxf(m, gl[f][j]);
        float s = 0.f;
        #pragma unroll
        for (int j = 0; j < 8; j++) s += __expf(gl[f][j] - m);
        float wv = __expf(gl[f][k] - m) / s;
        wsm[f][k] = wv;
        ws[tid] = wv;
    }
    if (tid < 992) {
        int f = tid >> 5, c = tid & 31;
        float s = 0.f;
        #pragma unroll 8
        for (int v = 0; v < V_; v++) s += __expf(st[(f * V_ + v) * C_ + c]);
        lse_self[f][c] = __logf(s);
    }
    __syncthreads();
    if (tid < 32) {
        int c = tid;
        float scl = 0.f;
        #pragma unroll
        for (int j = 0; j < C_; j++) scl += __expf(cl[j]);
        float lse_cl = __logf(scl);
        float s0 = 0.f;
        #pragma unroll 8
        for (int v = 0; v < V_; v++) s0 += __expf(t0[v * C_ + c]);
        float lse_t0 = __logf(s0);
        float acc = cl[c] - lse_cl - lse_t0;
        for (int f = 0; f < 31; f++) acc -= wsm[f][0] * lse_self[f][c];
        ws[256 + c] = acc;
    }
}

// ------- Kernel B (fused): lse over pair_tables + fold into G ---------------
// thread per (j, v, c); j = f-k. Each lse element belongs to exactly one j.
// G[j,v,c] = (j==0 ? t0[v,c] : w[j-1][0]*st[j-1,v,c]) - sum_k w[j+k][k+1]*lse[(j+k)*7+k, v, c]
__global__ __launch_bounds__(256)
void build_g_kernel(const float* __restrict__ t0, const float* __restrict__ st,
                    const float* __restrict__ pt, const float* __restrict__ ws,
                    float* __restrict__ G) {
    int idx = blockIdx.x * 256 + threadIdx.x;   // < 32*64*32 = 65536
    int c = idx & 31, v = (idx >> 5) & 63, j = idx >> 11;
    int nk = min(KP_, 31 - j);                  // k valid while f=j+k < 31 (j==31 -> 0)
    const float* bp[KP_];
    #pragma unroll
    for (int k = 0; k < KP_; k++) {
        int f = j + k;
        int fk = f * KP_ + k;
        bp[k] = pt + (fk * (V_ * V_) + v) * C_ + c;   // + a*(V_*C_) walks the self axis
    }
    float s[KP_];
    #pragma unroll
    for (int k = 0; k < KP_; k++) s[k] = 0.f;
    for (int a = 0; a < V_; a += 2) {
        float l0[KP_], l1[KP_];
        #pragma unroll
        for (int k = 0; k < KP_; k++) if (k < nk) {
            l0[k] = bp[k][a * (V_ * C_)];
            l1[k] = bp[k][(a + 1) * (V_ * C_)];
        }
        #pragma unroll
        for (int k = 0; k < KP_; k++) if (k < nk) {
            s[k] += __expf(l0[k]);
            s[k] += __expf(l1[k]);
        }
    }
    float g = 0.f;
    #pragma unroll
    for (int k = 0; k < KP_; k++) if (k < nk)
        g -= ws[(j + k) * 8 + k + 1] * __logf(s[k]);
    if (j == 0) g += t0[v * C_ + c];
    else        g += ws[(j - 1) * 8] * st[((j - 1) * V_ + v) * C_ + c];
    G[idx] = g;
}

// ------------------------- Kernel C: main gather ----------------------------
// grid = 4096 blocks; block = 256 threads = 4 f-quarters x 2 batch rows x 32 c.
// q = tid>>6 is wave-uniform (no divergence). LDS tree-combine, plain store.
__global__ __launch_bounds__(256)
void main_kernel(const int* __restrict__ x, const float* __restrict__ pt,
                 const float* __restrict__ ws, float* __restrict__ out) {
    __shared__ int   xsh[64];        // 2 rows x 32 features
    __shared__ float wsh[248];
    __shared__ float offsh[32];
    __shared__ float part[3][64];
    int tid = threadIdx.x;
    if (tid < 64)  xsh[tid] = x[blockIdx.x * 64 + tid];
    if (tid < 248) wsh[tid] = ws[tid];
    if (tid < 32)  offsh[tid] = ws[256 + tid];
    __syncthreads();

    const float* __restrict__ G = ws + WS_G;
    int q = tid >> 6;                 // wave id / f-quarter
    int r = (tid >> 5) & 1;           // local batch row
    int c = tid & 31;
    const int* xrow = &xsh[r * 32];
    float acc = 0.f;

    // G part: 8 j's per quarter
    #pragma unroll
    for (int jj = 0; jj < 8; jj++) {
        int j = q * 8 + jj;
        acc += G[(j * V_ + xrow[j]) * C_ + c];
    }

    if (q == 0) {
        acc += offsh[c];
        // triangular: f=0..5, kmax=f+1
        for (int f = 0; f < 6; f++) {
            int xv = xrow[f + 1];
            const float* bp = pt + ((f * KP_) * V_ + xv) * (V_ * C_) + c;
            float pv[6];
            for (int k = 0; k <= f; k++)
                pv[k] = bp[k * (V_ * V_ * C_) + xrow[f - k] * C_];
            for (int k = 0; k <= f; k++)
                acc += wsh[f * 8 + k + 1] * pv[k];
        }
        #pragma unroll 2
        for (int f = 6; f < 10; f++) {
            int xv = xrow[f + 1];
            const float* bp = pt + ((f * KP_) * V_ + xv) * (V_ * C_) + c;
            float pv[KP_];
            #pragma unroll
            for (int k = 0; k < KP_; k++)
                pv[k] = bp[k * (V_ * V_ * C_) + xrow[f - k] * C_];
            #pragma unroll
            for (int k = 0; k < KP_; k++)
                acc += wsh[f * 8 + k + 1] * pv[k];
        }
    } else {
        // f ranges: q1:[10,17) q2:[17,24) q3:[24,31) — 7 f's x 7 k's = 49 loads
        int fbeg = 10 + (q - 1) * 7;
        #pragma unroll 2
        for (int ff = 0; ff < 7; ff++) {
            int f = fbeg + ff;
            int xv = xrow[f + 1];
            const float* bp = pt + ((f * KP_) * V_ + xv) * (V_ * C_) + c;
            float pv[KP_];
            #pragma unroll
            for (int k = 0; k < KP_; k++)
                pv[k] = bp[k * (V_ * V_ * C_) + xrow[f - k] * C_];
            #pragma unroll
            for (int k = 0; k < KP_; k++)
                acc += wsh[f * 8 + k + 1] * pv[k];
        }
    }

    // combine quarters
    if (q > 0) part[q - 1][r * 32 + c] = acc;
    __syncthreads();
    if (q == 0) {
        acc += part[0][tid] + part[1][tid] + part[2][tid];
        out[blockIdx.x * 64 + tid] = acc;
    }
}

extern "C" void kernel_launch(void* const* d_in, const int* in_sizes, int n_in,
                              void* d_out, int out_size, void* d_ws, size_t ws_size,
                              hipStream_t stream) {
    const int*   x   = (const int*)  d_in[0];
    // d_in[1] = training (unused)
    const float* cl  = (const float*)d_in[2];
    const float* t0  = (const float*)d_in[3];
    const float* st  = (const float*)d_in[4];
    const float* pt  = (const float*)d_in[5];
    const float* sl  = (const float*)d_in[6];
    const float* un  = (const float*)d_in[7];
    // d_in[8] cond_index, d_in[9] valid_mask: deterministic, computed analytically
    float* ws  = (float*)d_ws;
    float* out = (float*)d_out;

    prep_kernel<<<1, 1024, 0, stream>>>(cl, t0, st, sl, un, ws);
    build_g_kernel<<<256, 256, 0, stream>>>(t0, st, pt, ws, ws + WS_G);
    main_kernel<<<4096, 256, 0, stream>>>(x, pt, ws, out);
}

// Round 4
// 230.903 us; speedup vs baseline: 1.2236x; 1.0007x over previous
//
#include <hip/hip_runtime.h>
#include <math.h>

// Problem constants
#define B_  8192
#define F_  32
#define V_  64
#define C_  32
#define KP_ 7
#define EPS_ 1e-6f

// ws layout (floats):
//  [0,248)           : w[f][k]  (31 x 8 gumbel-softmax weights); [248,256) zeros (pad weight slot)
//  [256,288)         : offc[c]
//  [288,488)         : etab[200] (ints): packed (widx<<20)|(fk<<12)|(fi<<6)|ci, 25 per q
//  [512,66048)       : G[j][v][c]   (folded t0/self/pair-lse table, 256 KB)
//  [66048,510464)    : lse[fk][xc][c]  (1.78 MB)
#define WS_OFF  256
#define WS_ETAB 288
#define WS_G    512
#define WS_LSE  66048

__device__ const int d_split[9] = {0, 25, 50, 74, 99, 123, 148, 172, 196};

// ---------------- Kernel A: tiny prep (1 block, 1024 threads) ----------------
__global__ __launch_bounds__(1024)
void prep_kernel(const float* __restrict__ cl, const float* __restrict__ t0,
                 const float* __restrict__ st, const float* __restrict__ sl,
                 const float* __restrict__ un, float* __restrict__ ws) {
    __shared__ float gl[31][8];
    __shared__ float wsm[31][8];
    __shared__ float lse_self[31][32];
    int tid = threadIdx.x;

    if (tid < 248) {
        int f = tid >> 3, k = tid & 7;
        int kmax = min(f + 1, KP_);
        bool valid = (k <= kmax);
        float u = un[tid];
        float g = -__logf(-__logf(u + EPS_) + EPS_);
        gl[f][k] = valid ? (sl[tid] + g) : -INFINITY;
    }
    if (tid >= 248 && tid < 256) ws[tid] = 0.f;   // zero pad weight slot
    // entry table: 8 q-groups x 25 entries
    if (tid < 200) {
        int q = tid / 25, i = tid % 25;
        int g = d_split[q] + i;
        int packed;
        if (g < d_split[q + 1]) {
            int f = 0, base = 0;
            for (;;) { int cnt = min(f + 1, KP_); if (g < base + cnt) break; base += cnt; f++; }
            int k = g - base;
            packed = ((f * 8 + k + 1) << 20) | ((f * KP_ + k) << 12) | ((f + 1) << 6) | (f - k);
        } else {
            packed = (248 << 20);   // weight=0, fk=0, fi=0, ci=0
        }
        ((int*)ws)[WS_ETAB + tid] = packed;
    }
    __syncthreads();
    if (tid < 248) {
        int f = tid >> 3, k = tid & 7;
        float m = -INFINITY;
        #pragma unroll
        for (int j = 0; j < 8; j++) m = fmaxf(m, gl[f][j]);
        float s = 0.f;
        #pragma unroll
        for (int j = 0; j < 8; j++) s += __expf(gl[f][j] - m);
        float wv = __expf(gl[f][k] - m) / s;
        wsm[f][k] = wv;
        ws[tid] = wv;
    }
    if (tid < 992) {
        int f = tid >> 5, c = tid & 31;
        float s = 0.f;
        #pragma unroll 8
        for (int v = 0; v < V_; v++) s += __expf(st[(f * V_ + v) * C_ + c]);
        lse_self[f][c] = __logf(s);
    }
    __syncthreads();
    if (tid < 32) {
        int c = tid;
        float scl = 0.f;
        #pragma unroll
        for (int j = 0; j < C_; j++) scl += __expf(cl[j]);
        float lse_cl = __logf(scl);
        float s0 = 0.f;
        #pragma unroll 8
        for (int v = 0; v < V_; v++) s0 += __expf(t0[v * C_ + c]);
        float lse_t0 = __logf(s0);
        float acc = cl[c] - lse_cl - lse_t0;
        for (int f = 0; f < 31; f++) acc -= wsm[f][0] * lse_self[f][c];
        ws[WS_OFF + c] = acc;
    }
}

// ------------- Kernel B1: lse over pair_tables self axis, float4 ------------
// thread per (fk, xc, c4); 217*64*8 = 111104 threads = 434 blocks
__global__ __launch_bounds__(256)
void lse_kernel(const float* __restrict__ pt, float* __restrict__ ws) {
    int idx = blockIdx.x * 256 + threadIdx.x;
    int c4 = idx & 7, v = (idx >> 3) & 63, fk = idx >> 9;   // fk 0..216
    const float* p = pt + (size_t)fk * (V_ * V_ * C_) + v * C_ + c4 * 4;
    float4 s = make_float4(0.f, 0.f, 0.f, 0.f);
    for (int a = 0; a < V_; a += 8) {
        float4 l[8];
        #pragma unroll
        for (int i = 0; i < 8; i++)
            l[i] = *(const float4*)(p + (a + i) * (V_ * C_));
        #pragma unroll
        for (int i = 0; i < 8; i++) {
            s.x += __expf(l[i].x); s.y += __expf(l[i].y);
            s.z += __expf(l[i].z); s.w += __expf(l[i].w);
        }
    }
    float4 r;
    r.x = __logf(s.x); r.y = __logf(s.y); r.z = __logf(s.z); r.w = __logf(s.w);
    ((float4*)(ws + WS_LSE))[idx] = r;
}

// ------------- Kernel B2: fold lse + t0 + self into G, float4 ---------------
// thread per (j, v, c4); 32*64*8 = 16384 threads = 64 blocks
__global__ __launch_bounds__(256)
void foldg_kernel(const float* __restrict__ t0, const float* __restrict__ st,
                  float* __restrict__ ws) {
    int idx = blockIdx.x * 256 + threadIdx.x;
    int c4 = idx & 7, v = (idx >> 3) & 63, j = idx >> 9;    // j 0..31
    int nk = min(KP_, 31 - j);
    const float4* lse4 = (const float4*)(ws + WS_LSE);
    float4 g;
    if (j == 0) {
        g = ((const float4*)t0)[v * 8 + c4];
    } else {
        float w0 = ws[(j - 1) * 8];
        float4 sv = ((const float4*)st)[((j - 1) * V_ + v) * 8 + c4];
        g.x = w0 * sv.x; g.y = w0 * sv.y; g.z = w0 * sv.z; g.w = w0 * sv.w;
    }
    for (int k = 0; k < nk; k++) {
        int f = j + k;
        float wv = ws[f * 8 + k + 1];
        float4 lv = lse4[((f * KP_ + k) * V_ + v) * 8 + c4];
        g.x -= wv * lv.x; g.y -= wv * lv.y; g.z -= wv * lv.z; g.w -= wv * lv.w;
    }
    ((float4*)(ws + WS_G))[idx] = g;
}

// ------------------------- Kernel C: main gather, float4 --------------------
// block = 256 threads = 8 q x 4 rows x 8 c4; grid = 2048 blocks (8192 waves)
__global__ __launch_bounds__(256)
void main_kernel(const int* __restrict__ x, const float* __restrict__ pt,
                 const float* __restrict__ ws, float* __restrict__ out) {
    __shared__ int   xsh[4 * 33];      // 4 rows, stride 33 (bank spread)
    __shared__ float wsh[256];
    __shared__ int   etab[200];
    __shared__ float4 offv[8];
    __shared__ float4 part[7][32];
    int tid = threadIdx.x;
    if (tid < 128) xsh[(tid >> 5) * 33 + (tid & 31)] = x[blockIdx.x * 128 + tid];
    wsh[tid] = ws[tid];
    if (tid < 200) etab[tid] = ((const int*)ws)[WS_ETAB + tid];
    if (tid < 8)   offv[tid] = ((const float4*)(ws + WS_OFF))[tid];
    __syncthreads();

    const float4* __restrict__ G4 = (const float4*)(ws + WS_G);
    int q  = tid >> 5;
    int r  = (tid >> 3) & 3;
    int c4 = tid & 7;
    const int* xrow = &xsh[r * 33];
    float4 acc = make_float4(0.f, 0.f, 0.f, 0.f);

    // G part: 4 j's per q (L2-resident 256 KB table)
    #pragma unroll
    for (int jj = 0; jj < 4; jj++) {
        int j = q * 4 + jj;
        float4 gv = G4[(j * V_ + xrow[j]) * 8 + c4];
        acc.x += gv.x; acc.y += gv.y; acc.z += gv.z; acc.w += gv.w;
    }
    if (q == 0) {
        float4 ov = offv[c4];
        acc.x += ov.x; acc.y += ov.y; acc.z += ov.z; acc.w += ov.w;
    }

    // pair part: 25 table entries per q, chunks of 5 for ILP
    int beg = q * 25;
    #pragma unroll
    for (int ch = 0; ch < 5; ch++) {
        float4 pv[5];
        float  wt[5];
        #pragma unroll
        for (int i = 0; i < 5; i++) {
            int pk = etab[beg + ch * 5 + i];
            int ci = pk & 63, fi = (pk >> 6) & 63;
            int fk = (pk >> 12) & 255, widx = (pk >> 20) & 255;
            int xv = xrow[fi], xc = xrow[ci];
            pv[i] = *(const float4*)(pt + ((size_t)(fk * V_ + xv) * V_ + xc) * C_ + c4 * 4);
            wt[i] = wsh[widx];
        }
        #pragma unroll
        for (int i = 0; i < 5; i++) {
            acc.x += wt[i] * pv[i].x; acc.y += wt[i] * pv[i].y;
            acc.z += wt[i] * pv[i].z; acc.w += wt[i] * pv[i].w;
        }
    }

    // combine 8 q-partials
    if (q > 0) part[q - 1][r * 8 + c4] = acc;
    __syncthreads();
    if (q == 0) {
        #pragma unroll
        for (int p = 0; p < 7; p++) {
            float4 pv = part[p][r * 8 + c4];
            acc.x += pv.x; acc.y += pv.y; acc.z += pv.z; acc.w += pv.w;
        }
        ((float4*)out)[(blockIdx.x * 4 + r) * 8 + c4] = acc;
    }
}

extern "C" void kernel_launch(void* const* d_in, const int* in_sizes, int n_in,
                              void* d_out, int out_size, void* d_ws, size_t ws_size,
                              hipStream_t stream) {
    const int*   x   = (const int*)  d_in[0];
    // d_in[1] = training (unused)
    const float* cl  = (const float*)d_in[2];
    const float* t0  = (const float*)d_in[3];
    const float* st  = (const float*)d_in[4];
    const float* pt  = (const float*)d_in[5];
    const float* sl  = (const float*)d_in[6];
    const float* un  = (const float*)d_in[7];
    // d_in[8] cond_index, d_in[9] valid_mask: deterministic, computed analytically
    float* ws  = (float*)d_ws;
    float* out = (float*)d_out;

    prep_kernel<<<1, 1024, 0, stream>>>(cl, t0, st, sl, un, ws);
    lse_kernel<<<434, 256, 0, stream>>>(pt, ws);
    foldg_kernel<<<64, 256, 0, stream>>>(t0, st, ws);
    main_kernel<<<2048, 256, 0, stream>>>(x, pt, ws, out);
}